// Round 6
// baseline (289.337 us; speedup 1.0000x reference)
//
#include <hip/hip_runtime.h>

#define NFR   4
#define NLOCC 2048
#define NNEIN 64
#define EMB   128
#define PDIM  64
#define NH    8
#define LNEPS 1e-5f
#define NROW  (NFR*NLOCC)   // 8192

// workspace layout (float offsets)
#define WS_Q   0
#define WS_K   (NROW*EMB)            // 1,048,576
#define WS_FV  (2*NROW*EMB)          // 2,097,152 : fv[row][8]
#define WS_G   (2*NROW*EMB + NROW*NH) // 2,162,688 : G[8][64], SG[8], C[8]

__device__ __forceinline__ void fma4(float4& acc, const float4 a, const float4 b) {
    acc.x = fmaf(a.x, b.x, acc.x);
    acc.y = fmaf(a.y, b.y, acc.y);
    acc.z = fmaf(a.z, b.z, acc.z);
    acc.w = fmaf(a.w, b.w, acc.w);
}
__device__ __forceinline__ void fma4s(float4& acc, const float s, const float4 b) {
    acc.x = fmaf(s, b.x, acc.x);
    acc.y = fmaf(s, b.y, acc.y);
    acc.z = fmaf(s, b.z, acc.z);
    acc.w = fmaf(s, b.w, acc.w);
}
__device__ __forceinline__ float hsum4(const float4 a) {
    return (a.x + a.y) + (a.z + a.w);
}
__device__ __forceinline__ float dot4(const float4 a, const float4 b) {
    return fmaf(a.x, b.x, fmaf(a.y, b.y, fmaf(a.z, b.z, a.w * b.w)));
}
__device__ __forceinline__ float4 scale4(const float4 a, const float s) {
    return make_float4(a.x*s, a.y*s, a.z*s, a.w*s);
}

// DPP cross-lane move on the VALU pipe (NOT ds_bpermute). CTRL:
//   0xB1 = quad_perm(1,0,3,2)  == xor 1
//   0x4E = quad_perm(2,3,0,1)  == xor 2
//   0x111/0x112/0x114/0x118 = row_shr 1/2/4/8 (bound_ctrl=1 -> 0 shifted in)
//   0x142/0x143 = row_bcast15 / row_bcast31 (unwritten lanes get old=0)
// 64-lane sum via row_shr chain + bcast15 + bcast31 is valid read at lane 63.
template<int CTRL>
__device__ __forceinline__ float dppf(float x) {
    return __int_as_float(__builtin_amdgcn_update_dpp(
        0, __float_as_int(x), CTRL, 0xF, 0xF, true));
}

// ---------------- Kernel 1: LN(query) + q,k projections + fv + G/SG/C ----------------
__global__ __launch_bounds__(256, 2) void qkfv_kernel(
    const float* __restrict__ query,
    const float* __restrict__ ln_g, const float* __restrict__ ln_b,
    const float* __restrict__ Wq, const float* __restrict__ Wk,
    const float* __restrict__ Wv, const float* __restrict__ Wforce,
    const float* __restrict__ pn_g, const float* __restrict__ pn_b,
    const float* __restrict__ Wbias, const float* __restrict__ bbias,
    float* __restrict__ ws)
{
    __shared__ float  gb_s[2][EMB];
    __shared__ float  qn_s[16*132];
    __shared__ float  wt_s[2][16*132];
    __shared__ float4 wvf_s4[8*33];      // Wv_f[h][ch], padded rows (33 float4)
    const int t = threadIdx.x;
    const int rowbase = blockIdx.x * 16;

    if (t < 64) {
        const float* src = (t < 32) ? ln_g : ln_b;
        ((float4*)gb_s[t >> 5])[t & 31] = ((const float4*)src)[t & 31];
    }

    // ---- block 0: G / SG / C side-table for kernel 2 ----
    if (blockIdx.x == 0) {
        if (t < 128) {
            const float4 wb4 = ((const float4*)Wbias)[t];       // Wbias[8][64]
            const float4 pg4 = ((const float4*)pn_g)[t & 15];
            ((float4*)(ws + WS_G))[t] =
                make_float4(wb4.x*pg4.x, wb4.y*pg4.y, wb4.z*pg4.z, wb4.w*pg4.w);
        } else if (t < 192) {
            const int h = (t - 128) >> 3, s8 = (t - 128) & 7;
            float sg = 0.f, cb = 0.f;
            #pragma unroll
            for (int k = 0; k < 8; ++k) {
                const int p = s8*8 + k;
                const float wb = Wbias[h*PDIM + p];
                sg = fmaf(pn_g[p], wb, sg);
                cb = fmaf(pn_b[p], wb, cb);
            }
            sg += __shfl_xor(sg, 1, 64); sg += __shfl_xor(sg, 2, 64); sg += __shfl_xor(sg, 4, 64);
            cb += __shfl_xor(cb, 1, 64); cb += __shfl_xor(cb, 2, 64); cb += __shfl_xor(cb, 4, 64);
            if (s8 == 0) {
                ws[WS_G + 512 + h] = sg;            // SG[h]
                ws[WS_G + 520 + h] = cb + bbias[h]; // C[h]
            }
        }
    }

    // Wv_f[h][e] = sum_d Wforce[h*16+d] * Wv[h*16+d][e]
    {
        const int h = t >> 5, ch = t & 31;
        float4 acc = make_float4(0.f, 0.f, 0.f, 0.f);
        #pragma unroll
        for (int d = 0; d < 16; ++d) {
            const float wf = Wforce[h*16 + d];
            const float4 wv = ((const float4*)(Wv + (size_t)(h*16 + d)*EMB))[ch];
            fma4s(acc, wf, wv);
        }
        wvf_s4[h*33 + ch] = acc;
    }

    // LayerNorm: 16 threads per row, 8 floats each
    const int r   = t >> 4;
    const int seg = t & 15;
    float4 x0 = ((const float4*)query)[(size_t)(rowbase + r)*32 + seg*2 + 0];
    float4 x1 = ((const float4*)query)[(size_t)(rowbase + r)*32 + seg*2 + 1];
    float s  = (x0.x + x0.y) + (x0.z + x0.w) + (x1.x + x1.y) + (x1.z + x1.w);
    float ss = x0.x*x0.x + x0.y*x0.y + x0.z*x0.z + x0.w*x0.w
             + x1.x*x1.x + x1.y*x1.y + x1.z*x1.z + x1.w*x1.w;
    #pragma unroll
    for (int m = 1; m < 16; m <<= 1) {
        s  += __shfl_xor(s,  m, 64);
        ss += __shfl_xor(ss, m, 64);
    }
    const float mean = s * (1.0f / 128.0f);
    const float var  = ss * (1.0f / 128.0f) - mean * mean;
    const float rstd = rsqrtf(var + LNEPS);
    __syncthreads();   // gb_s + wvf_s4 ready

    {
        const int c0 = seg * 8;
        float4 o0, o1;
        o0.x = (x0.x - mean)*rstd*gb_s[0][c0+0] + gb_s[1][c0+0];
        o0.y = (x0.y - mean)*rstd*gb_s[0][c0+1] + gb_s[1][c0+1];
        o0.z = (x0.z - mean)*rstd*gb_s[0][c0+2] + gb_s[1][c0+2];
        o0.w = (x0.w - mean)*rstd*gb_s[0][c0+3] + gb_s[1][c0+3];
        o1.x = (x1.x - mean)*rstd*gb_s[0][c0+4] + gb_s[1][c0+4];
        o1.y = (x1.y - mean)*rstd*gb_s[0][c0+5] + gb_s[1][c0+5];
        o1.z = (x1.z - mean)*rstd*gb_s[0][c0+6] + gb_s[1][c0+6];
        o1.w = (x1.w - mean)*rstd*gb_s[0][c0+7] + gb_s[1][c0+7];
        ((float4*)qn_s)[r*33 + seg*2 + 0] = o0;
        ((float4*)qn_s)[r*33 + seg*2 + 1] = o1;
    }
    __syncthreads();

    const int rp = t >> 5;
    const int r0 = rp * 2;
    const int cq = t & 31;
    const int sc0 = t >> 2;
    const int si0 = t & 3;
    const float4* qn4 = (const float4*)qn_s;

    for (int w = 0; w < 2; ++w) {
        const float4* W4 = (const float4*)((w == 0) ? Wq : Wk);
        float4 acc0 = make_float4(0.f,0.f,0.f,0.f);
        float4 acc1 = make_float4(0.f,0.f,0.f,0.f);
        {
            float4 g0 = W4[(size_t)sc0*32 + si0];
            float4 g1 = W4[(size_t)(sc0+64)*32 + si0];
            float* wt = wt_s[0];
            wt[(si0*4+0)*132 + sc0] = g0.x; wt[(si0*4+1)*132 + sc0] = g0.y;
            wt[(si0*4+2)*132 + sc0] = g0.z; wt[(si0*4+3)*132 + sc0] = g0.w;
            wt[(si0*4+0)*132 + sc0+64] = g1.x; wt[(si0*4+1)*132 + sc0+64] = g1.y;
            wt[(si0*4+2)*132 + sc0+64] = g1.z; wt[(si0*4+3)*132 + sc0+64] = g1.w;
        }
        __syncthreads();
        #pragma unroll
        for (int tau = 0; tau < 8; ++tau) {
            const int buf = tau & 1;
            float4 ng0, ng1;
            if (tau < 7) {
                ng0 = W4[(size_t)sc0*32 + (tau+1)*4 + si0];
                ng1 = W4[(size_t)(sc0+64)*32 + (tau+1)*4 + si0];
            }
            const float4* wt4 = (const float4*)wt_s[buf];
            #pragma unroll
            for (int e4 = 0; e4 < 4; ++e4) {
                float4 a0 = qn4[r0*33 + tau*4 + e4];
                float4 a1 = qn4[(r0+1)*33 + tau*4 + e4];
                const float* a0p = (const float*)&a0;
                const float* a1p = (const float*)&a1;
                #pragma unroll
                for (int ee = 0; ee < 4; ++ee) {
                    const float4 wv = wt4[(e4*4+ee)*33 + cq];
                    fma4s(acc0, a0p[ee], wv);
                    fma4s(acc1, a1p[ee], wv);
                }
            }
            if (tau < 7) {
                float* wt = wt_s[buf ^ 1];
                wt[(si0*4+0)*132 + sc0] = ng0.x; wt[(si0*4+1)*132 + sc0] = ng0.y;
                wt[(si0*4+2)*132 + sc0] = ng0.z; wt[(si0*4+3)*132 + sc0] = ng0.w;
                wt[(si0*4+0)*132 + sc0+64] = ng1.x; wt[(si0*4+1)*132 + sc0+64] = ng1.y;
                wt[(si0*4+2)*132 + sc0+64] = ng1.z; wt[(si0*4+3)*132 + sc0+64] = ng1.w;
            }
            __syncthreads();
        }
        const float sc = (w == 0) ? 0.25f : 1.0f;   // HD^-0.5 folded into q
        float4* dst = (float4*)(ws + (w == 0 ? WS_Q : WS_K));
        dst[(size_t)(rowbase + r0)*32 + cq]     = scale4(acc0, sc);
        dst[(size_t)(rowbase + r0 + 1)*32 + cq] = scale4(acc1, sc);
    }

    // fv[row][h] = dot128(qn[row], Wv_f[h])
    if (t < 128) {
        const int rr = t >> 3, h = t & 7;
        float4 acc = make_float4(0.f,0.f,0.f,0.f);
        #pragma unroll
        for (int ch = 0; ch < 32; ++ch)
            fma4(acc, qn4[rr*33 + ch], wvf_s4[h*33 + ch]);
        ws[WS_FV + (size_t)(rowbase + rr)*NH + h] = hsum4(acc);
    }
}

// ---------------- Kernel 2: attn + force — 4-row software pipeline ----------------
// 2048 blocks x 256 threads, 3 blocks/CU. Each block processes 4 rows of one
// frame; the independent load set for row r+1 (nlist/pair/q/mask/dp) is issued
// into a second register set at the TOP of row r, and the K/fv gathers for r+1
// issue right after phase B frees kk. Register loads stay in flight across
// s_barrier (T14 pattern), so each row's compute waits only on loads issued a
// full row (~1500 cy) earlier. G staged once per block (amortized 4x).
// LDS arrays single-buffered: barrier(2) separates row r's readers from row
// r+1's writers. Per-row compute mappings identical to the verified round-5 code.
#define ISSUE_INDEP(slot, rrow)                                                     \
    {                                                                               \
        _Pragma("unroll")                                                           \
        for (int i = 0; i < 8; ++i)                                                 \
            jr[slot][i] = nlist[(size_t)(rrow)*NNEIN + ((w << 4) | (i << 1) | half)];\
        jn[slot] = nlist[(size_t)(rrow)*NNEIN + n];                                 \
        q4[slot] = ((const float4*)(ws + WS_Q))[(size_t)(rrow)*32 + c];             \
        const size_t mbase = (((size_t)(fr*NH + hh))*NLOCC + ((rrow) & (NLOCC-1)))*NNEIN; \
        ma[slot] = attn_mask[mbase + i32];                                          \
        mb[slot] = attn_mask[mbase + i32 + 32];                                     \
        const float4* prp = (const float4*)(pair + ((size_t)(rrow)*NNEIN + n)*PDIM) + sub*4; \
        pr[slot][0] = prp[0]; pr[slot][1] = prp[1];                                 \
        pr[slot][2] = prp[2]; pr[slot][3] = prp[3];                                 \
        const float* dpp_ = delta_pos + (size_t)(rrow)*192;                         \
        dpa[slot][0] = dpp_[i32*3+0]; dpa[slot][1] = dpp_[i32*3+1]; dpa[slot][2] = dpp_[i32*3+2]; \
        dpb[slot][0] = dpp_[(i32+32)*3+0]; dpb[slot][1] = dpp_[(i32+32)*3+1]; dpb[slot][2] = dpp_[(i32+32)*3+2]; \
    }

#define ISSUE_GATHER(slot)                                                          \
    {                                                                               \
        _Pragma("unroll")                                                           \
        for (int i = 0; i < 8; ++i) kk[i] = k4[(size_t)jr[slot][i]*32 + c];         \
        fv2[slot] = ((const float2*)(fvb + (size_t)jn[slot]*NH))[sub];              \
    }

__global__ __launch_bounds__(256, 3) void attn_force_kernel(
    const float* __restrict__ pair, const int* __restrict__ nlist,
    const float* __restrict__ delta_pos, const float* __restrict__ attn_mask,
    const float* __restrict__ ws, float* __restrict__ out)
{
    __shared__ float  logit_s[NNEIN*9];   // [n][9] stride coprime with 32
    __shared__ float  bias_s[NNEIN*9];
    __shared__ float  fv_s[NNEIN*9];
    __shared__ float4 gw_s4[4*128];       // per-wave private G[8][16] copy (8 KiB)
    __shared__ float  fpart[4][3];

    const int t    = threadIdx.x;
    const int row0 = blockIdx.x << 2;     // 4 rows per block, same frame (4 | 2048)
    const int fr   = row0 >> 11;
    const int w    = t >> 6;
    const int lane = t & 63;
    const int n    = t >> 2;              // pair/fv neighbor
    const int sub  = t & 3;
    const int half = lane >> 5;           // QK mapping
    const int c    = lane & 31;
    const int hh   = t >> 5;              // softmax head
    const int i32  = lane & 31;           // softmax neighbor index

    // wave-private G copy (write+read within same wave: no __syncthreads)
    {
        const float4* Gg = (const float4*)(ws + WS_G);
        gw_s4[(w << 7) | lane]        = Gg[lane];
        gw_s4[(w << 7) | (64 + lane)] = Gg[64 + lane];
    }

    // per-row register state, two slots (prefetch pipeline)
    int    jr[2][8];
    int    jn[2];
    float4 q4[2];
    float  ma[2], mb[2];
    float4 pr[2][4];
    float  dpa[2][3], dpb[2][3];
    float2 fv2[2];
    float4 kk[8];                         // single-buffered: refilled after phase B

    const float4* k4  = (const float4*)(ws + WS_K) + (size_t)(fr << 11)*32;
    const float*  fvb = ws + WS_FV + ((size_t)(fr << 11))*NH;

    // ---- prologue: row 0 loads ----
    ISSUE_INDEP(0, row0);
    ISSUE_GATHER(0);

    #pragma unroll
    for (int r = 0; r < 4; ++r) {
        const int cur = r & 1, nxt = cur ^ 1;

        // stage fv for this row (register arrived a row ago; cross-mapping read
        // happens after barrier (1))
        fv_s[n*9 + sub*2]     = fv2[cur].x;
        fv_s[n*9 + sub*2 + 1] = fv2[cur].y;

        // prefetch row r+1's independent loads (HBM pair hidden under this row)
        if (r < 3) ISSUE_INDEP(nxt, row0 + r + 1);

        // ---------------- phase B: QK -> logit_s (consumes kk) ----------------
        #pragma unroll
        for (int i = 0; i < 8; ++i) {
            float pp = dot4(kk[i], q4[cur]);
            pp += dppf<0xB1>(pp);          // xor 1 (VALU)
            pp += dppf<0x4E>(pp);          // xor 2 (VALU)
            if ((c & 3) == 0)
                logit_s[((w << 4) | (i << 1) | half)*9 + (c >> 2)] = pp;
        }

        // kk free -> issue row r+1's K/fv gathers (hidden under phase A + softmax)
        if (r < 3) ISSUE_GATHER(nxt);

        // ---------------- phase A: pair LN + bias -> bias_s ----------------
        {
            const float4 p0 = pr[cur][0], p1 = pr[cur][1];
            const float4 p2 = pr[cur][2], p3 = pr[cur][3];
            float s  = hsum4(p0) + hsum4(p1) + hsum4(p2) + hsum4(p3);
            float ss = dot4(p0,p0) + dot4(p1,p1) + dot4(p2,p2) + dot4(p3,p3);
            s  += dppf<0xB1>(s);  s  += dppf<0x4E>(s);
            ss += dppf<0xB1>(ss); ss += dppf<0x4E>(ss);

            float d[NH];
            #pragma unroll
            for (int h = 0; h < NH; ++h) d[h] = 0.f;
            const float4* gw = &gw_s4[w << 7];
            const float4 prq[4] = {p0, p1, p2, p3};
            #pragma unroll
            for (int q = 0; q < 4; ++q) {
                #pragma unroll
                for (int h = 0; h < NH; ++h)
                    d[h] += dot4(prq[q], gw[h*16 + sub*4 + q]);
            }
            #pragma unroll
            for (int h = 0; h < NH; ++h) {
                d[h] += dppf<0xB1>(d[h]);
                d[h] += dppf<0x4E>(d[h]);
            }
            const float mean = s * (1.0f / 64.0f);
            const float var  = ss * (1.0f / 64.0f) - mean * mean;
            const float rstd = rsqrtf(var + LNEPS);
            const float* SGp = ws + WS_G + 512;   // uniform -> s_load
            const int h0 = sub*2, h1 = h0 + 1;
            bias_s[n*9 + h0] = rstd*(d[h0] - mean*SGp[h0]) + SGp[8 + h0];
            bias_s[n*9 + h1] = rstd*(d[h1] - mean*SGp[h1]) + SGp[8 + h1];
        }
        __syncthreads();   // (1) logit_s, bias_s, fv_s ready

        // ---------------- softmax + PV + force (hh/i32 mapping) ----------------
        {
            const float a = logit_s[i32*9 + hh]        + bias_s[i32*9 + hh]        + ma[cur];
            const float b = logit_s[(i32 + 32)*9 + hh] + bias_s[(i32 + 32)*9 + hh] + mb[cur];
            float m = fmaxf(a, b);
            m = fmaxf(m, __shfl_xor(m, 16, 64));
            m = fmaxf(m, __shfl_xor(m,  8, 64));
            m = fmaxf(m, __shfl_xor(m,  4, 64));
            m = fmaxf(m, dppf<0x4E>(m));
            m = fmaxf(m, dppf<0xB1>(m));
            const float ea = __expf(a - m), eb = __expf(b - m);
            float sum = ea + eb;
            sum += __shfl_xor(sum, 16, 64);
            sum += __shfl_xor(sum,  8, 64);
            sum += __shfl_xor(sum,  4, 64);
            sum += dppf<0x4E>(sum);
            sum += dppf<0xB1>(sum);
            const float inv = 1.0f / sum;
            // own-head contribution ONLY (the 64-lane reduce below covers both heads)
            const float ca = ea * inv * fv_s[i32*9 + hh];
            const float cb = eb * inv * fv_s[(i32 + 32)*9 + hh];

            float f0 = ca*dpa[cur][0] + cb*dpb[cur][0];
            float f1 = ca*dpa[cur][1] + cb*dpb[cur][1];
            float f2 = ca*dpa[cur][2] + cb*dpb[cur][2];
            // 64-lane wave reduce on VALU: row_shr chain then row_bcast; total in lane 63
            f0 += dppf<0x111>(f0); f0 += dppf<0x112>(f0); f0 += dppf<0x114>(f0); f0 += dppf<0x118>(f0);
            f0 += dppf<0x142>(f0); f0 += dppf<0x143>(f0);
            f1 += dppf<0x111>(f1); f1 += dppf<0x112>(f1); f1 += dppf<0x114>(f1); f1 += dppf<0x118>(f1);
            f1 += dppf<0x142>(f1); f1 += dppf<0x143>(f1);
            f2 += dppf<0x111>(f2); f2 += dppf<0x112>(f2); f2 += dppf<0x114>(f2); f2 += dppf<0x118>(f2);
            f2 += dppf<0x142>(f2); f2 += dppf<0x143>(f2);
            if (lane == 63) {
                fpart[w][0] = f0; fpart[w][1] = f1; fpart[w][2] = f2;
            }
        }
        __syncthreads();   // (2) fpart ready; also fences LDS reuse for next row

        if (t < 3)
            out[(size_t)(row0 + r)*3 + t] = fpart[0][t] + fpart[1][t] + fpart[2][t] + fpart[3][t];
    }
}

extern "C" void kernel_launch(void* const* d_in, const int* in_sizes, int n_in,
                              void* d_out, int out_size, void* d_ws, size_t ws_size,
                              hipStream_t stream) {
    const float* query     = (const float*)d_in[0];
    const float* pair      = (const float*)d_in[1];
    const int*   nlist     = (const int*)d_in[2];
    const float* delta_pos = (const float*)d_in[3];
    const float* attn_mask = (const float*)d_in[4];
    const float* ln_g      = (const float*)d_in[5];
    const float* ln_b      = (const float*)d_in[6];
    const float* pn_g      = (const float*)d_in[7];
    const float* pn_b      = (const float*)d_in[8];
    const float* Wq        = (const float*)d_in[9];
    const float* Wk        = (const float*)d_in[10];
    const float* Wv        = (const float*)d_in[11];
    const float* Wbias     = (const float*)d_in[12];
    const float* bbias     = (const float*)d_in[13];
    const float* Wforce    = (const float*)d_in[14];
    float* out = (float*)d_out;
    float* ws  = (float*)d_ws;

    qkfv_kernel<<<512, 256, 0, stream>>>(query, ln_g, ln_b, Wq, Wk, Wv, Wforce,
                                         pn_g, pn_b, Wbias, bbias, ws);
    attn_force_kernel<<<NROW/4, 256, 0, stream>>>(pair, nlist, delta_pos, attn_mask,
                                                  ws, out);
}

// Round 7
// 265.425 us; speedup vs baseline: 1.0901x; 1.0901x over previous
//
#include <hip/hip_runtime.h>

#define NFR   4
#define NLOCC 2048
#define NNEIN 64
#define EMB   128
#define PDIM  64
#define NH    8
#define LNEPS 1e-5f
#define NROW  (NFR*NLOCC)   // 8192

// workspace layout (float offsets)
#define WS_Q   0
#define WS_K   (NROW*EMB)            // 1,048,576
#define WS_FV  (2*NROW*EMB)          // 2,097,152 : fv[row][8]
#define WS_G   (2*NROW*EMB + NROW*NH) // 2,162,688 : G[8][64], SG[8], C[8]

__device__ __forceinline__ void fma4(float4& acc, const float4 a, const float4 b) {
    acc.x = fmaf(a.x, b.x, acc.x);
    acc.y = fmaf(a.y, b.y, acc.y);
    acc.z = fmaf(a.z, b.z, acc.z);
    acc.w = fmaf(a.w, b.w, acc.w);
}
__device__ __forceinline__ void fma4s(float4& acc, const float s, const float4 b) {
    acc.x = fmaf(s, b.x, acc.x);
    acc.y = fmaf(s, b.y, acc.y);
    acc.z = fmaf(s, b.z, acc.z);
    acc.w = fmaf(s, b.w, acc.w);
}
__device__ __forceinline__ float hsum4(const float4 a) {
    return (a.x + a.y) + (a.z + a.w);
}
__device__ __forceinline__ float dot4(const float4 a, const float4 b) {
    return fmaf(a.x, b.x, fmaf(a.y, b.y, fmaf(a.z, b.z, a.w * b.w)));
}
__device__ __forceinline__ float4 scale4(const float4 a, const float s) {
    return make_float4(a.x*s, a.y*s, a.z*s, a.w*s);
}

// DPP cross-lane move on the VALU pipe (NOT ds_bpermute). CTRL:
//   0xB1 = quad_perm(1,0,3,2)  == xor 1
//   0x4E = quad_perm(2,3,0,1)  == xor 2
//   0x111/0x112/0x114/0x118 = row_shr 1/2/4/8 (bound_ctrl=1 -> 0 shifted in)
//   0x142/0x143 = row_bcast15 / row_bcast31 (unwritten lanes get old=0)
// 64-lane sum via row_shr chain + bcast15 + bcast31 is valid read at lane 63.
template<int CTRL>
__device__ __forceinline__ float dppf(float x) {
    return __int_as_float(__builtin_amdgcn_update_dpp(
        0, __float_as_int(x), CTRL, 0xF, 0xF, true));
}

// ---------------- Kernel 1: LN(query) + q,k projections + fv + G/SG/C ----------------
__global__ __launch_bounds__(256, 2) void qkfv_kernel(
    const float* __restrict__ query,
    const float* __restrict__ ln_g, const float* __restrict__ ln_b,
    const float* __restrict__ Wq, const float* __restrict__ Wk,
    const float* __restrict__ Wv, const float* __restrict__ Wforce,
    const float* __restrict__ pn_g, const float* __restrict__ pn_b,
    const float* __restrict__ Wbias, const float* __restrict__ bbias,
    float* __restrict__ ws)
{
    __shared__ float  gb_s[2][EMB];
    __shared__ float  qn_s[16*132];
    __shared__ float  wt_s[2][16*132];
    __shared__ float4 wvf_s4[8*33];      // Wv_f[h][ch], padded rows (33 float4)
    const int t = threadIdx.x;
    const int rowbase = blockIdx.x * 16;

    if (t < 64) {
        const float* src = (t < 32) ? ln_g : ln_b;
        ((float4*)gb_s[t >> 5])[t & 31] = ((const float4*)src)[t & 31];
    }

    // ---- block 0: G / SG / C side-table for kernel 2 ----
    if (blockIdx.x == 0) {
        if (t < 128) {
            const float4 wb4 = ((const float4*)Wbias)[t];       // Wbias[8][64]
            const float4 pg4 = ((const float4*)pn_g)[t & 15];
            ((float4*)(ws + WS_G))[t] =
                make_float4(wb4.x*pg4.x, wb4.y*pg4.y, wb4.z*pg4.z, wb4.w*pg4.w);
        } else if (t < 192) {
            const int h = (t - 128) >> 3, s8 = (t - 128) & 7;
            float sg = 0.f, cb = 0.f;
            #pragma unroll
            for (int k = 0; k < 8; ++k) {
                const int p = s8*8 + k;
                const float wb = Wbias[h*PDIM + p];
                sg = fmaf(pn_g[p], wb, sg);
                cb = fmaf(pn_b[p], wb, cb);
            }
            sg += __shfl_xor(sg, 1, 64); sg += __shfl_xor(sg, 2, 64); sg += __shfl_xor(sg, 4, 64);
            cb += __shfl_xor(cb, 1, 64); cb += __shfl_xor(cb, 2, 64); cb += __shfl_xor(cb, 4, 64);
            if (s8 == 0) {
                ws[WS_G + 512 + h] = sg;            // SG[h]
                ws[WS_G + 520 + h] = cb + bbias[h]; // C[h]
            }
        }
    }

    // Wv_f[h][e] = sum_d Wforce[h*16+d] * Wv[h*16+d][e]
    {
        const int h = t >> 5, ch = t & 31;
        float4 acc = make_float4(0.f, 0.f, 0.f, 0.f);
        #pragma unroll
        for (int d = 0; d < 16; ++d) {
            const float wf = Wforce[h*16 + d];
            const float4 wv = ((const float4*)(Wv + (size_t)(h*16 + d)*EMB))[ch];
            fma4s(acc, wf, wv);
        }
        wvf_s4[h*33 + ch] = acc;
    }

    // LayerNorm: 16 threads per row, 8 floats each
    const int r   = t >> 4;
    const int seg = t & 15;
    float4 x0 = ((const float4*)query)[(size_t)(rowbase + r)*32 + seg*2 + 0];
    float4 x1 = ((const float4*)query)[(size_t)(rowbase + r)*32 + seg*2 + 1];
    float s  = (x0.x + x0.y) + (x0.z + x0.w) + (x1.x + x1.y) + (x1.z + x1.w);
    float ss = x0.x*x0.x + x0.y*x0.y + x0.z*x0.z + x0.w*x0.w
             + x1.x*x1.x + x1.y*x1.y + x1.z*x1.z + x1.w*x1.w;
    #pragma unroll
    for (int m = 1; m < 16; m <<= 1) {
        s  += __shfl_xor(s,  m, 64);
        ss += __shfl_xor(ss, m, 64);
    }
    const float mean = s * (1.0f / 128.0f);
    const float var  = ss * (1.0f / 128.0f) - mean * mean;
    const float rstd = rsqrtf(var + LNEPS);
    __syncthreads();   // gb_s + wvf_s4 ready

    {
        const int c0 = seg * 8;
        float4 o0, o1;
        o0.x = (x0.x - mean)*rstd*gb_s[0][c0+0] + gb_s[1][c0+0];
        o0.y = (x0.y - mean)*rstd*gb_s[0][c0+1] + gb_s[1][c0+1];
        o0.z = (x0.z - mean)*rstd*gb_s[0][c0+2] + gb_s[1][c0+2];
        o0.w = (x0.w - mean)*rstd*gb_s[0][c0+3] + gb_s[1][c0+3];
        o1.x = (x1.x - mean)*rstd*gb_s[0][c0+4] + gb_s[1][c0+4];
        o1.y = (x1.y - mean)*rstd*gb_s[0][c0+5] + gb_s[1][c0+5];
        o1.z = (x1.z - mean)*rstd*gb_s[0][c0+6] + gb_s[1][c0+6];
        o1.w = (x1.w - mean)*rstd*gb_s[0][c0+7] + gb_s[1][c0+7];
        ((float4*)qn_s)[r*33 + seg*2 + 0] = o0;
        ((float4*)qn_s)[r*33 + seg*2 + 1] = o1;
    }
    __syncthreads();

    const int rp = t >> 5;
    const int r0 = rp * 2;
    const int cq = t & 31;
    const int sc0 = t >> 2;
    const int si0 = t & 3;
    const float4* qn4 = (const float4*)qn_s;

    for (int w = 0; w < 2; ++w) {
        const float4* W4 = (const float4*)((w == 0) ? Wq : Wk);
        float4 acc0 = make_float4(0.f,0.f,0.f,0.f);
        float4 acc1 = make_float4(0.f,0.f,0.f,0.f);
        {
            float4 g0 = W4[(size_t)sc0*32 + si0];
            float4 g1 = W4[(size_t)(sc0+64)*32 + si0];
            float* wt = wt_s[0];
            wt[(si0*4+0)*132 + sc0] = g0.x; wt[(si0*4+1)*132 + sc0] = g0.y;
            wt[(si0*4+2)*132 + sc0] = g0.z; wt[(si0*4+3)*132 + sc0] = g0.w;
            wt[(si0*4+0)*132 + sc0+64] = g1.x; wt[(si0*4+1)*132 + sc0+64] = g1.y;
            wt[(si0*4+2)*132 + sc0+64] = g1.z; wt[(si0*4+3)*132 + sc0+64] = g1.w;
        }
        __syncthreads();
        #pragma unroll
        for (int tau = 0; tau < 8; ++tau) {
            const int buf = tau & 1;
            float4 ng0, ng1;
            if (tau < 7) {
                ng0 = W4[(size_t)sc0*32 + (tau+1)*4 + si0];
                ng1 = W4[(size_t)(sc0+64)*32 + (tau+1)*4 + si0];
            }
            const float4* wt4 = (const float4*)wt_s[buf];
            #pragma unroll
            for (int e4 = 0; e4 < 4; ++e4) {
                float4 a0 = qn4[r0*33 + tau*4 + e4];
                float4 a1 = qn4[(r0+1)*33 + tau*4 + e4];
                const float* a0p = (const float*)&a0;
                const float* a1p = (const float*)&a1;
                #pragma unroll
                for (int ee = 0; ee < 4; ++ee) {
                    const float4 wv = wt4[(e4*4+ee)*33 + cq];
                    fma4s(acc0, a0p[ee], wv);
                    fma4s(acc1, a1p[ee], wv);
                }
            }
            if (tau < 7) {
                float* wt = wt_s[buf ^ 1];
                wt[(si0*4+0)*132 + sc0] = ng0.x; wt[(si0*4+1)*132 + sc0] = ng0.y;
                wt[(si0*4+2)*132 + sc0] = ng0.z; wt[(si0*4+3)*132 + sc0] = ng0.w;
                wt[(si0*4+0)*132 + sc0+64] = ng1.x; wt[(si0*4+1)*132 + sc0+64] = ng1.y;
                wt[(si0*4+2)*132 + sc0+64] = ng1.z; wt[(si0*4+3)*132 + sc0+64] = ng1.w;
            }
            __syncthreads();
        }
        const float sc = (w == 0) ? 0.25f : 1.0f;   // HD^-0.5 folded into q
        float4* dst = (float4*)(ws + (w == 0 ? WS_Q : WS_K));
        dst[(size_t)(rowbase + r0)*32 + cq]     = scale4(acc0, sc);
        dst[(size_t)(rowbase + r0 + 1)*32 + cq] = scale4(acc1, sc);
    }

    // fv[row][h] = dot128(qn[row], Wv_f[h])
    if (t < 128) {
        const int rr = t >> 3, h = t & 7;
        float4 acc = make_float4(0.f,0.f,0.f,0.f);
        #pragma unroll
        for (int ch = 0; ch < 32; ++ch)
            fma4(acc, qn4[rr*33 + ch], wvf_s4[h*33 + ch]);
        ws[WS_FV + (size_t)(rowbase + rr)*NH + h] = hsum4(acc);
    }
}

// ---------------- Kernel 2: attn + force — 4-row pipeline, STRAIGHT-LINE ----------------
// 2048 blocks x 256 threads, 3 blocks/CU. Round-6 lesson (rule #20): the r-loop
// version kept `slot` runtime -> all pipeline state spilled to scratch
// (WRITE_SIZE 320 KB -> 29 MB, VGPR stuck at 84). Here the 4 row bodies are
// straight-line macro instantiations with LITERAL slot indices (0/1); every
// array access is compile-time constant, so the double-buffered prefetch state
// lives in registers. Per-row compute identical to the verified round-5 kernel.
// Schedule per row: stage fv -> ISSUE_INDEP(next row: pair/q/mask/dp, HBM
// latency hides under B+A+softmax) -> phase B consumes kk -> ISSUE_GATHER(next
// row) into freed kk -> phase A -> barrier -> softmax -> barrier -> out.

#define ISSUE_INDEP(S, rrow)                                                        \
    {                                                                               \
        jnS[S] = nlist[(size_t)(rrow)*NNEIN + n];                                   \
        q4S[S] = ((const float4*)(ws + WS_Q))[(size_t)(rrow)*32 + c];               \
        const size_t mbase = (((size_t)(fr*NH + hh))*NLOCC + ((rrow) & (NLOCC-1)))*NNEIN; \
        maS[S] = attn_mask[mbase + i32];                                            \
        mbS[S] = attn_mask[mbase + i32 + 32];                                       \
        const float4* prp = (const float4*)(pair + ((size_t)(rrow)*NNEIN + n)*PDIM) + sub*4; \
        prS[S][0] = prp[0]; prS[S][1] = prp[1];                                     \
        prS[S][2] = prp[2]; prS[S][3] = prp[3];                                     \
        const float* dpp_ = delta_pos + (size_t)(rrow)*192;                         \
        dpaS[S][0] = dpp_[i32*3+0]; dpaS[S][1] = dpp_[i32*3+1]; dpaS[S][2] = dpp_[i32*3+2]; \
        dpbS[S][0] = dpp_[(i32+32)*3+0]; dpbS[S][1] = dpp_[(i32+32)*3+1]; dpbS[S][2] = dpp_[(i32+32)*3+2]; \
    }

// nlist row was warmed by ISSUE_INDEP's jn touch; re-load jr here (L1/L2-hot)
// so the 8 indices don't occupy registers across the row.
#define ISSUE_GATHER(S, rrow)                                                       \
    {                                                                               \
        int j0 = nlist[(size_t)(rrow)*NNEIN + ((w << 4) | 0 | half)];               \
        int j1 = nlist[(size_t)(rrow)*NNEIN + ((w << 4) | 2 | half)];               \
        int j2 = nlist[(size_t)(rrow)*NNEIN + ((w << 4) | 4 | half)];               \
        int j3 = nlist[(size_t)(rrow)*NNEIN + ((w << 4) | 6 | half)];               \
        int j4 = nlist[(size_t)(rrow)*NNEIN + ((w << 4) | 8 | half)];               \
        int j5 = nlist[(size_t)(rrow)*NNEIN + ((w << 4) | 10 | half)];              \
        int j6 = nlist[(size_t)(rrow)*NNEIN + ((w << 4) | 12 | half)];              \
        int j7 = nlist[(size_t)(rrow)*NNEIN + ((w << 4) | 14 | half)];              \
        kk[0] = k4[(size_t)j0*32 + c]; kk[1] = k4[(size_t)j1*32 + c];               \
        kk[2] = k4[(size_t)j2*32 + c]; kk[3] = k4[(size_t)j3*32 + c];               \
        kk[4] = k4[(size_t)j4*32 + c]; kk[5] = k4[(size_t)j5*32 + c];               \
        kk[6] = k4[(size_t)j6*32 + c]; kk[7] = k4[(size_t)j7*32 + c];               \
        fvS[S] = ((const float2*)(fvb + (size_t)jnS[S]*NH))[sub];                   \
    }

#define ROW_BODY(CUR, NXT, rowc, PF)                                                \
    {                                                                               \
        fv_s[n*9 + sub*2]     = fvS[CUR].x;                                         \
        fv_s[n*9 + sub*2 + 1] = fvS[CUR].y;                                         \
        if (PF) ISSUE_INDEP(NXT, (rowc) + 1);                                       \
        /* phase B: QK -> logit_s (consumes kk) */                                  \
        _Pragma("unroll")                                                           \
        for (int i = 0; i < 8; ++i) {                                               \
            float pp = dot4(kk[i], q4S[CUR]);                                       \
            pp += dppf<0xB1>(pp);                                                   \
            pp += dppf<0x4E>(pp);                                                   \
            if ((c & 3) == 0)                                                       \
                logit_s[((w << 4) | (i << 1) | half)*9 + (c >> 2)] = pp;            \
        }                                                                           \
        if (PF) ISSUE_GATHER(NXT, (rowc) + 1);                                      \
        /* phase A: pair LN + bias -> bias_s */                                     \
        {                                                                           \
            const float4 p0 = prS[CUR][0], p1 = prS[CUR][1];                        \
            const float4 p2 = prS[CUR][2], p3 = prS[CUR][3];                        \
            float s  = hsum4(p0) + hsum4(p1) + hsum4(p2) + hsum4(p3);               \
            float ss = dot4(p0,p0) + dot4(p1,p1) + dot4(p2,p2) + dot4(p3,p3);       \
            s  += dppf<0xB1>(s);  s  += dppf<0x4E>(s);                              \
            ss += dppf<0xB1>(ss); ss += dppf<0x4E>(ss);                             \
            float d[NH];                                                            \
            _Pragma("unroll")                                                       \
            for (int h = 0; h < NH; ++h) d[h] = 0.f;                                \
            const float4* gw = &gw_s4[w << 7];                                      \
            _Pragma("unroll")                                                       \
            for (int h = 0; h < NH; ++h) {                                          \
                d[h] += dot4(p0, gw[h*16 + sub*4 + 0]);                             \
                d[h] += dot4(p1, gw[h*16 + sub*4 + 1]);                             \
                d[h] += dot4(p2, gw[h*16 + sub*4 + 2]);                             \
                d[h] += dot4(p3, gw[h*16 + sub*4 + 3]);                             \
            }                                                                       \
            _Pragma("unroll")                                                       \
            for (int h = 0; h < NH; ++h) {                                          \
                d[h] += dppf<0xB1>(d[h]);                                           \
                d[h] += dppf<0x4E>(d[h]);                                           \
            }                                                                       \
            const float mean = s * (1.0f / 64.0f);                                  \
            const float var  = ss * (1.0f / 64.0f) - mean * mean;                   \
            const float rstd = rsqrtf(var + LNEPS);                                 \
            const float* SGp = ws + WS_G + 512;                                     \
            const int h0 = sub*2, h1 = h0 + 1;                                      \
            bias_s[n*9 + h0] = rstd*(d[h0] - mean*SGp[h0]) + SGp[8 + h0];           \
            bias_s[n*9 + h1] = rstd*(d[h1] - mean*SGp[h1]) + SGp[8 + h1];           \
        }                                                                           \
        __syncthreads();   /* (1) logit_s, bias_s, fv_s ready */                    \
        /* softmax + PV + force (hh/i32 mapping) */                                 \
        {                                                                           \
            const float a = logit_s[i32*9 + hh]        + bias_s[i32*9 + hh]        + maS[CUR]; \
            const float b = logit_s[(i32 + 32)*9 + hh] + bias_s[(i32 + 32)*9 + hh] + mbS[CUR]; \
            float m = fmaxf(a, b);                                                  \
            m = fmaxf(m, __shfl_xor(m, 16, 64));                                    \
            m = fmaxf(m, __shfl_xor(m,  8, 64));                                    \
            m = fmaxf(m, __shfl_xor(m,  4, 64));                                    \
            m = fmaxf(m, dppf<0x4E>(m));                                            \
            m = fmaxf(m, dppf<0xB1>(m));                                            \
            const float ea = __expf(a - m), eb = __expf(b - m);                     \
            float sum = ea + eb;                                                    \
            sum += __shfl_xor(sum, 16, 64);                                         \
            sum += __shfl_xor(sum,  8, 64);                                         \
            sum += __shfl_xor(sum,  4, 64);                                         \
            sum += dppf<0x4E>(sum);                                                 \
            sum += dppf<0xB1>(sum);                                                 \
            const float inv = 1.0f / sum;                                           \
            const float ca = ea * inv * fv_s[i32*9 + hh];                           \
            const float cb = eb * inv * fv_s[(i32 + 32)*9 + hh];                    \
            float f0 = ca*dpaS[CUR][0] + cb*dpbS[CUR][0];                           \
            float f1 = ca*dpaS[CUR][1] + cb*dpbS[CUR][1];                           \
            float f2 = ca*dpaS[CUR][2] + cb*dpbS[CUR][2];                           \
            f0 += dppf<0x111>(f0); f0 += dppf<0x112>(f0); f0 += dppf<0x114>(f0); f0 += dppf<0x118>(f0); \
            f0 += dppf<0x142>(f0); f0 += dppf<0x143>(f0);                           \
            f1 += dppf<0x111>(f1); f1 += dppf<0x112>(f1); f1 += dppf<0x114>(f1); f1 += dppf<0x118>(f1); \
            f1 += dppf<0x142>(f1); f1 += dppf<0x143>(f1);                           \
            f2 += dppf<0x111>(f2); f2 += dppf<0x112>(f2); f2 += dppf<0x114>(f2); f2 += dppf<0x118>(f2); \
            f2 += dppf<0x142>(f2); f2 += dppf<0x143>(f2);                           \
            if (lane == 63) {                                                       \
                fpart[w][0] = f0; fpart[w][1] = f1; fpart[w][2] = f2;               \
            }                                                                       \
        }                                                                           \
        __syncthreads();   /* (2) fpart ready; fences LDS reuse for next row */     \
        if (t < 3)                                                                  \
            out[(size_t)(rowc)*3 + t] = fpart[0][t] + fpart[1][t] + fpart[2][t] + fpart[3][t]; \
    }

__global__ __launch_bounds__(256, 3) void attn_force_kernel(
    const float* __restrict__ pair, const int* __restrict__ nlist,
    const float* __restrict__ delta_pos, const float* __restrict__ attn_mask,
    const float* __restrict__ ws, float* __restrict__ out)
{
    __shared__ float  logit_s[NNEIN*9];   // [n][9] stride coprime with 32
    __shared__ float  bias_s[NNEIN*9];
    __shared__ float  fv_s[NNEIN*9];
    __shared__ float4 gw_s4[4*128];       // per-wave private G[8][16] copy (8 KiB)
    __shared__ float  fpart[4][3];

    const int t    = threadIdx.x;
    const int row0 = blockIdx.x << 2;     // 4 rows per block, same frame (4 | 2048)
    const int fr   = row0 >> 11;
    const int w    = t >> 6;
    const int lane = t & 63;
    const int n    = t >> 2;              // pair/fv neighbor
    const int sub  = t & 3;
    const int half = lane >> 5;           // QK mapping
    const int c    = lane & 31;
    const int hh   = t >> 5;              // softmax head
    const int i32  = lane & 31;           // softmax neighbor index

    // wave-private G copy (write+read within same wave: no __syncthreads)
    {
        const float4* Gg = (const float4*)(ws + WS_G);
        gw_s4[(w << 7) | lane]        = Gg[lane];
        gw_s4[(w << 7) | (64 + lane)] = Gg[64 + lane];
    }

    // pipeline register state — two slots, ONLY literal indices below
    int    jnS[2];
    float4 q4S[2];
    float  maS[2], mbS[2];
    float4 prS[2][4];
    float  dpaS[2][3], dpbS[2][3];
    float2 fvS[2];
    float4 kk[8];                         // single-buffered: refilled after phase B

    const float4* k4  = (const float4*)(ws + WS_K) + (size_t)(fr << 11)*32;
    const float*  fvb = ws + WS_FV + ((size_t)(fr << 11))*NH;

    // prologue: row 0 loads
    ISSUE_INDEP(0, row0);
    ISSUE_GATHER(0, row0);

    // straight-line 4-row pipeline (no loop -> no runtime slot index -> no scratch)
    ROW_BODY(0, 1, row0 + 0, 1);
    ROW_BODY(1, 0, row0 + 1, 1);
    ROW_BODY(0, 1, row0 + 2, 1);
    ROW_BODY(1, 0, row0 + 3, 0);
}

extern "C" void kernel_launch(void* const* d_in, const int* in_sizes, int n_in,
                              void* d_out, int out_size, void* d_ws, size_t ws_size,
                              hipStream_t stream) {
    const float* query     = (const float*)d_in[0];
    const float* pair      = (const float*)d_in[1];
    const int*   nlist     = (const int*)d_in[2];
    const float* delta_pos = (const float*)d_in[3];
    const float* attn_mask = (const float*)d_in[4];
    const float* ln_g      = (const float*)d_in[5];
    const float* ln_b      = (const float*)d_in[6];
    const float* pn_g      = (const float*)d_in[7];
    const float* pn_b      = (const float*)d_in[8];
    const float* Wq        = (const float*)d_in[9];
    const float* Wk        = (const float*)d_in[10];
    const float* Wv        = (const float*)d_in[11];
    const float* Wbias     = (const float*)d_in[12];
    const float* bbias     = (const float*)d_in[13];
    const float* Wforce    = (const float*)d_in[14];
    float* out = (float*)d_out;
    float* ws  = (float*)d_ws;

    qkfv_kernel<<<512, 256, 0, stream>>>(query, ln_g, ln_b, Wq, Wk, Wv, Wforce,
                                         pn_g, pn_b, Wbias, bbias, ws);
    attn_force_kernel<<<NROW/4, 256, 0, stream>>>(pair, nlist, delta_pos, attn_mask,
                                                  ws, out);
}

// Round 8
// 253.002 us; speedup vs baseline: 1.1436x; 1.0491x over previous
//
#include <hip/hip_runtime.h>

#define NFR   4
#define NLOCC 2048
#define NNEIN 64
#define EMB   128
#define PDIM  64
#define NH    8
#define LNEPS 1e-5f
#define NROW  (NFR*NLOCC)   // 8192

// workspace layout (float offsets)
#define WS_Q   0
#define WS_K   (NROW*EMB)            // 1,048,576
#define WS_FV  (2*NROW*EMB)          // 2,097,152 : fv[row][8]
#define WS_G   (2*NROW*EMB + NROW*NH) // 2,162,688 : G[8][64], SG[8], C[8]

__device__ __forceinline__ void fma4(float4& acc, const float4 a, const float4 b) {
    acc.x = fmaf(a.x, b.x, acc.x);
    acc.y = fmaf(a.y, b.y, acc.y);
    acc.z = fmaf(a.z, b.z, acc.z);
    acc.w = fmaf(a.w, b.w, acc.w);
}
__device__ __forceinline__ void fma4s(float4& acc, const float s, const float4 b) {
    acc.x = fmaf(s, b.x, acc.x);
    acc.y = fmaf(s, b.y, acc.y);
    acc.z = fmaf(s, b.z, acc.z);
    acc.w = fmaf(s, b.w, acc.w);
}
__device__ __forceinline__ float hsum4(const float4 a) {
    return (a.x + a.y) + (a.z + a.w);
}
__device__ __forceinline__ float dot4(const float4 a, const float4 b) {
    return fmaf(a.x, b.x, fmaf(a.y, b.y, fmaf(a.z, b.z, a.w * b.w)));
}
__device__ __forceinline__ float4 scale4(const float4 a, const float s) {
    return make_float4(a.x*s, a.y*s, a.z*s, a.w*s);
}

// DPP cross-lane move on the VALU pipe (NOT ds_bpermute). CTRL:
//   0xB1 = quad_perm(1,0,3,2)  == xor 1
//   0x4E = quad_perm(2,3,0,1)  == xor 2
//   0x111/0x112/0x114/0x118 = row_shr 1/2/4/8 (bound_ctrl=1 -> 0 shifted in)
//   0x142/0x143 = row_bcast15 / row_bcast31 (unwritten lanes get old=0)
// 64-lane sum via row_shr chain + bcast15 + bcast31 is valid read at lane 63.
template<int CTRL>
__device__ __forceinline__ float dppf(float x) {
    return __int_as_float(__builtin_amdgcn_update_dpp(
        0, __float_as_int(x), CTRL, 0xF, 0xF, true));
}

// ---------------- Kernel 1: LN(query) + q,k projections + fv + G/SG/C ----------------
__global__ __launch_bounds__(256, 2) void qkfv_kernel(
    const float* __restrict__ query,
    const float* __restrict__ ln_g, const float* __restrict__ ln_b,
    const float* __restrict__ Wq, const float* __restrict__ Wk,
    const float* __restrict__ Wv, const float* __restrict__ Wforce,
    const float* __restrict__ pn_g, const float* __restrict__ pn_b,
    const float* __restrict__ Wbias, const float* __restrict__ bbias,
    float* __restrict__ ws)
{
    __shared__ float  gb_s[2][EMB];
    __shared__ float  qn_s[16*132];
    __shared__ float  wt_s[2][16*132];
    __shared__ float4 wvf_s4[8*33];      // Wv_f[h][ch], padded rows (33 float4)
    const int t = threadIdx.x;
    const int rowbase = blockIdx.x * 16;

    if (t < 64) {
        const float* src = (t < 32) ? ln_g : ln_b;
        ((float4*)gb_s[t >> 5])[t & 31] = ((const float4*)src)[t & 31];
    }

    // ---- block 0: G / SG / C side-table for kernel 2 ----
    if (blockIdx.x == 0) {
        if (t < 128) {
            const float4 wb4 = ((const float4*)Wbias)[t];       // Wbias[8][64]
            const float4 pg4 = ((const float4*)pn_g)[t & 15];
            ((float4*)(ws + WS_G))[t] =
                make_float4(wb4.x*pg4.x, wb4.y*pg4.y, wb4.z*pg4.z, wb4.w*pg4.w);
        } else if (t < 192) {
            const int h = (t - 128) >> 3, s8 = (t - 128) & 7;
            float sg = 0.f, cb = 0.f;
            #pragma unroll
            for (int k = 0; k < 8; ++k) {
                const int p = s8*8 + k;
                const float wb = Wbias[h*PDIM + p];
                sg = fmaf(pn_g[p], wb, sg);
                cb = fmaf(pn_b[p], wb, cb);
            }
            sg += __shfl_xor(sg, 1, 64); sg += __shfl_xor(sg, 2, 64); sg += __shfl_xor(sg, 4, 64);
            cb += __shfl_xor(cb, 1, 64); cb += __shfl_xor(cb, 2, 64); cb += __shfl_xor(cb, 4, 64);
            if (s8 == 0) {
                ws[WS_G + 512 + h] = sg;            // SG[h]
                ws[WS_G + 520 + h] = cb + bbias[h]; // C[h]
            }
        }
    }

    // Wv_f[h][e] = sum_d Wforce[h*16+d] * Wv[h*16+d][e]
    {
        const int h = t >> 5, ch = t & 31;
        float4 acc = make_float4(0.f, 0.f, 0.f, 0.f);
        #pragma unroll
        for (int d = 0; d < 16; ++d) {
            const float wf = Wforce[h*16 + d];
            const float4 wv = ((const float4*)(Wv + (size_t)(h*16 + d)*EMB))[ch];
            fma4s(acc, wf, wv);
        }
        wvf_s4[h*33 + ch] = acc;
    }

    // LayerNorm: 16 threads per row, 8 floats each
    const int r   = t >> 4;
    const int seg = t & 15;
    float4 x0 = ((const float4*)query)[(size_t)(rowbase + r)*32 + seg*2 + 0];
    float4 x1 = ((const float4*)query)[(size_t)(rowbase + r)*32 + seg*2 + 1];
    float s  = (x0.x + x0.y) + (x0.z + x0.w) + (x1.x + x1.y) + (x1.z + x1.w);
    float ss = x0.x*x0.x + x0.y*x0.y + x0.z*x0.z + x0.w*x0.w
             + x1.x*x1.x + x1.y*x1.y + x1.z*x1.z + x1.w*x1.w;
    #pragma unroll
    for (int m = 1; m < 16; m <<= 1) {
        s  += __shfl_xor(s,  m, 64);
        ss += __shfl_xor(ss, m, 64);
    }
    const float mean = s * (1.0f / 128.0f);
    const float var  = ss * (1.0f / 128.0f) - mean * mean;
    const float rstd = rsqrtf(var + LNEPS);
    __syncthreads();   // gb_s + wvf_s4 ready

    {
        const int c0 = seg * 8;
        float4 o0, o1;
        o0.x = (x0.x - mean)*rstd*gb_s[0][c0+0] + gb_s[1][c0+0];
        o0.y = (x0.y - mean)*rstd*gb_s[0][c0+1] + gb_s[1][c0+1];
        o0.z = (x0.z - mean)*rstd*gb_s[0][c0+2] + gb_s[1][c0+2];
        o0.w = (x0.w - mean)*rstd*gb_s[0][c0+3] + gb_s[1][c0+3];
        o1.x = (x1.x - mean)*rstd*gb_s[0][c0+4] + gb_s[1][c0+4];
        o1.y = (x1.y - mean)*rstd*gb_s[0][c0+5] + gb_s[1][c0+5];
        o1.z = (x1.z - mean)*rstd*gb_s[0][c0+6] + gb_s[1][c0+6];
        o1.w = (x1.w - mean)*rstd*gb_s[0][c0+7] + gb_s[1][c0+7];
        ((float4*)qn_s)[r*33 + seg*2 + 0] = o0;
        ((float4*)qn_s)[r*33 + seg*2 + 1] = o1;
    }
    __syncthreads();

    const int rp = t >> 5;
    const int r0 = rp * 2;
    const int cq = t & 31;
    const int sc0 = t >> 2;
    const int si0 = t & 3;
    const float4* qn4 = (const float4*)qn_s;

    for (int w = 0; w < 2; ++w) {
        const float4* W4 = (const float4*)((w == 0) ? Wq : Wk);
        float4 acc0 = make_float4(0.f,0.f,0.f,0.f);
        float4 acc1 = make_float4(0.f,0.f,0.f,0.f);
        {
            float4 g0 = W4[(size_t)sc0*32 + si0];
            float4 g1 = W4[(size_t)(sc0+64)*32 + si0];
            float* wt = wt_s[0];
            wt[(si0*4+0)*132 + sc0] = g0.x; wt[(si0*4+1)*132 + sc0] = g0.y;
            wt[(si0*4+2)*132 + sc0] = g0.z; wt[(si0*4+3)*132 + sc0] = g0.w;
            wt[(si0*4+0)*132 + sc0+64] = g1.x; wt[(si0*4+1)*132 + sc0+64] = g1.y;
            wt[(si0*4+2)*132 + sc0+64] = g1.z; wt[(si0*4+3)*132 + sc0+64] = g1.w;
        }
        __syncthreads();
        #pragma unroll
        for (int tau = 0; tau < 8; ++tau) {
            const int buf = tau & 1;
            float4 ng0, ng1;
            if (tau < 7) {
                ng0 = W4[(size_t)sc0*32 + (tau+1)*4 + si0];
                ng1 = W4[(size_t)(sc0+64)*32 + (tau+1)*4 + si0];
            }
            const float4* wt4 = (const float4*)wt_s[buf];
            #pragma unroll
            for (int e4 = 0; e4 < 4; ++e4) {
                float4 a0 = qn4[r0*33 + tau*4 + e4];
                float4 a1 = qn4[(r0+1)*33 + tau*4 + e4];
                const float* a0p = (const float*)&a0;
                const float* a1p = (const float*)&a1;
                #pragma unroll
                for (int ee = 0; ee < 4; ++ee) {
                    const float4 wv = wt4[(e4*4+ee)*33 + cq];
                    fma4s(acc0, a0p[ee], wv);
                    fma4s(acc1, a1p[ee], wv);
                }
            }
            if (tau < 7) {
                float* wt = wt_s[buf ^ 1];
                wt[(si0*4+0)*132 + sc0] = ng0.x; wt[(si0*4+1)*132 + sc0] = ng0.y;
                wt[(si0*4+2)*132 + sc0] = ng0.z; wt[(si0*4+3)*132 + sc0] = ng0.w;
                wt[(si0*4+0)*132 + sc0+64] = ng1.x; wt[(si0*4+1)*132 + sc0+64] = ng1.y;
                wt[(si0*4+2)*132 + sc0+64] = ng1.z; wt[(si0*4+3)*132 + sc0+64] = ng1.w;
            }
            __syncthreads();
        }
        const float sc = (w == 0) ? 0.25f : 1.0f;   // HD^-0.5 folded into q
        float4* dst = (float4*)(ws + (w == 0 ? WS_Q : WS_K));
        dst[(size_t)(rowbase + r0)*32 + cq]     = scale4(acc0, sc);
        dst[(size_t)(rowbase + r0 + 1)*32 + cq] = scale4(acc1, sc);
    }

    // fv[row][h] = dot128(qn[row], Wv_f[h])
    if (t < 128) {
        const int rr = t >> 3, h = t & 7;
        float4 acc = make_float4(0.f,0.f,0.f,0.f);
        #pragma unroll
        for (int ch = 0; ch < 32; ++ch)
            fma4(acc, qn4[rr*33 + ch], wvf_s4[h*33 + ch]);
        ws[WS_FV + (size_t)(rowbase + rr)*NH + h] = hsum4(acc);
    }
}

// ---------------- Kernel 2: attn + force — line-efficient pair reads ----------------
// 8192 blocks x 256 threads, 4 blocks/CU. Round-5 structure (one compute barrier,
// batched loads, DPP reductions) with ONE targeted change: the pair read is
// stride-4 interleaved so thread (n,sub) holds float4 indices {sub,4+sub,8+sub,
// 12+sub}. Each load instruction then reads one contiguous 64B line per row
// (16 fully-used lines/instr) instead of 16B from each of 64 lines -> pair
// line-requests drop 1024 -> 256 per block (~45% of the kernel's TCP work).
// Phase A compensates by indexing G as [q*4+sub]; the quad-reduce over sub
// still covers all 16 float4 positions, LN stats are order-agnostic.
__global__ __launch_bounds__(256, 4) void attn_force_kernel(
    const float* __restrict__ pair, const int* __restrict__ nlist,
    const float* __restrict__ delta_pos, const float* __restrict__ attn_mask,
    const float* __restrict__ ws, float* __restrict__ out)
{
    __shared__ float  logit_s[NNEIN*9];   // [n][9] stride coprime with 32
    __shared__ float  bias_s[NNEIN*9];
    __shared__ float  fv_s[NNEIN*9];
    __shared__ float  dp_s[192];
    __shared__ float4 gw_s4[4*128];       // per-wave private G[8][16] copy (8 KiB)
    __shared__ float  fpart[4][3];

    const int t    = threadIdx.x;
    const int bid  = blockIdx.x;          // == row
    const int fr   = bid >> 11;
    const int l    = bid & (NLOCC - 1);
    const int w    = t >> 6;
    const int lane = t & 63;
    const int n    = t >> 2;              // pair/fv neighbor
    const int sub  = t & 3;
    const int half = lane >> 5;           // QK mapping
    const int c    = lane & 31;
    const int hh   = t >> 5;              // softmax head
    const int i32  = lane & 31;           // softmax neighbor index

    // ---------------- load batch 1: nlist indices ----------------
    int jr[8];
    #pragma unroll
    for (int i = 0; i < 8; ++i)
        jr[i] = nlist[(size_t)bid*NNEIN + ((w << 4) | (i << 1) | half)];
    const int jn = nlist[(size_t)bid*NNEIN + n];

    // ---------------- load batch 2: independent streams ----------------
    const float4 q4c = ((const float4*)(ws + WS_Q))[(size_t)bid*32 + c];

    const size_t mbase = (((size_t)(fr*NH + hh))*NLOCC + l)*NNEIN;
    const float ma = attn_mask[mbase + i32];
    const float mb = attn_mask[mbase + i32 + 32];

    // pair row, stride-4 interleave: instr q reads one contiguous 64B line/row
    const float4* pr4 = (const float4*)(pair + ((size_t)bid*NNEIN + n)*PDIM) + sub;
    const float4 p0 = pr4[0];    // float4 index sub
    const float4 p1 = pr4[4];    // 4 + sub
    const float4 p2 = pr4[8];    // 8 + sub
    const float4 p3 = pr4[12];   // 12 + sub

    // wave-private G copy (write+read within same wave: no __syncthreads)
    {
        const float4* Gg = (const float4*)(ws + WS_G);
        gw_s4[(w << 7) | lane]        = Gg[lane];
        gw_s4[(w << 7) | (64 + lane)] = Gg[64 + lane];
    }

    if (t >= 192 && t < 240)
        ((float4*)dp_s)[t - 192] = ((const float4*)(delta_pos + (size_t)bid*192))[t - 192];

    // ---------------- load batch 3: gathers (indices have arrived) ----------------
    const float4* k4 = (const float4*)(ws + WS_K) + (size_t)(fr << 11)*32;
    float4 kk[8];
    #pragma unroll
    for (int i = 0; i < 8; ++i) kk[i] = k4[(size_t)jr[i]*32 + c];

    {
        const float2 fv2 = ((const float2*)(ws + WS_FV + ((size_t)(fr << 11) + jn)*NH))[sub];
        fv_s[n*9 + sub*2]     = fv2.x;
        fv_s[n*9 + sub*2 + 1] = fv2.y;
    }

    // ---------------- phase B first (consumes and frees kk) ----------------
    {
        #pragma unroll
        for (int i = 0; i < 8; ++i) {
            float pp = dot4(kk[i], q4c);
            pp += dppf<0xB1>(pp);          // xor 1 (VALU)
            pp += dppf<0x4E>(pp);          // xor 2 (VALU)
            if ((c & 3) == 0)
                logit_s[((w << 4) | (i << 1) | half)*9 + (c >> 2)] = pp;
        }
    }

    // ---------------- phase A: pair LN + bias (G from wave-private LDS) ----------------
    {
        float s  = hsum4(p0) + hsum4(p1) + hsum4(p2) + hsum4(p3);
        float ss = dot4(p0,p0) + dot4(p1,p1) + dot4(p2,p2) + dot4(p3,p3);
        s  += dppf<0xB1>(s);  s  += dppf<0x4E>(s);
        ss += dppf<0xB1>(ss); ss += dppf<0x4E>(ss);

        float d[NH];
        #pragma unroll
        for (int h = 0; h < NH; ++h) d[h] = 0.f;
        const float4* gw = &gw_s4[w << 7];
        // thread holds float4 indices q*4+sub -> G indexed the same way
        #pragma unroll
        for (int h = 0; h < NH; ++h) {
            d[h] += dot4(p0, gw[h*16 + 0*4 + sub]);
            d[h] += dot4(p1, gw[h*16 + 1*4 + sub]);
            d[h] += dot4(p2, gw[h*16 + 2*4 + sub]);
            d[h] += dot4(p3, gw[h*16 + 3*4 + sub]);
        }
        #pragma unroll
        for (int h = 0; h < NH; ++h) {
            d[h] += dppf<0xB1>(d[h]);
            d[h] += dppf<0x4E>(d[h]);
        }
        const float mean = s * (1.0f / 64.0f);
        const float var  = ss * (1.0f / 64.0f) - mean * mean;
        const float rstd = rsqrtf(var + LNEPS);
        const float* SGp = ws + WS_G + 512;   // uniform -> s_load
        const int h0 = sub*2, h1 = h0 + 1;
        bias_s[n*9 + h0] = rstd*(d[h0] - mean*SGp[h0]) + SGp[8 + h0];
        bias_s[n*9 + h1] = rstd*(d[h1] - mean*SGp[h1]) + SGp[8 + h1];
    }
    __syncthreads();   // (1) logit_s, bias_s, fv_s, dp_s ready

    // ---------------- softmax + PV + force (hh/i32 mapping) ----------------
    {
        const float a = logit_s[i32*9 + hh]        + bias_s[i32*9 + hh]        + ma;
        const float b = logit_s[(i32 + 32)*9 + hh] + bias_s[(i32 + 32)*9 + hh] + mb;
        float m = fmaxf(a, b);
        m = fmaxf(m, __shfl_xor(m, 16, 64));
        m = fmaxf(m, __shfl_xor(m,  8, 64));
        m = fmaxf(m, __shfl_xor(m,  4, 64));
        m = fmaxf(m, dppf<0x4E>(m));
        m = fmaxf(m, dppf<0xB1>(m));
        const float ea = __expf(a - m), eb = __expf(b - m);
        float sum = ea + eb;
        sum += __shfl_xor(sum, 16, 64);
        sum += __shfl_xor(sum,  8, 64);
        sum += __shfl_xor(sum,  4, 64);
        sum += dppf<0x4E>(sum);
        sum += dppf<0xB1>(sum);
        const float inv = 1.0f / sum;
        // own-head contribution ONLY (the 64-lane reduce below covers both heads)
        const float ca = ea * inv * fv_s[i32*9 + hh];
        const float cb = eb * inv * fv_s[(i32 + 32)*9 + hh];

        const float dpax = dp_s[i32*3 + 0],      dpay = dp_s[i32*3 + 1],      dpaz = dp_s[i32*3 + 2];
        const float dpbx = dp_s[(i32+32)*3 + 0], dpby = dp_s[(i32+32)*3 + 1], dpbz = dp_s[(i32+32)*3 + 2];
        float f0 = ca*dpax + cb*dpbx;
        float f1 = ca*dpay + cb*dpby;
        float f2 = ca*dpaz + cb*dpbz;
        // 64-lane wave reduce on VALU: row_shr chain then row_bcast; total in lane 63
        f0 += dppf<0x111>(f0); f0 += dppf<0x112>(f0); f0 += dppf<0x114>(f0); f0 += dppf<0x118>(f0);
        f0 += dppf<0x142>(f0); f0 += dppf<0x143>(f0);
        f1 += dppf<0x111>(f1); f1 += dppf<0x112>(f1); f1 += dppf<0x114>(f1); f1 += dppf<0x118>(f1);
        f1 += dppf<0x142>(f1); f1 += dppf<0x143>(f1);
        f2 += dppf<0x111>(f2); f2 += dppf<0x112>(f2); f2 += dppf<0x114>(f2); f2 += dppf<0x118>(f2);
        f2 += dppf<0x142>(f2); f2 += dppf<0x143>(f2);
        if (lane == 63) {
            fpart[w][0] = f0; fpart[w][1] = f1; fpart[w][2] = f2;
        }
    }
    __syncthreads();   // (2)

    if (t < 3)
        out[(size_t)bid*3 + t] = fpart[0][t] + fpart[1][t] + fpart[2][t] + fpart[3][t];
}

extern "C" void kernel_launch(void* const* d_in, const int* in_sizes, int n_in,
                              void* d_out, int out_size, void* d_ws, size_t ws_size,
                              hipStream_t stream) {
    const float* query     = (const float*)d_in[0];
    const float* pair      = (const float*)d_in[1];
    const int*   nlist     = (const int*)d_in[2];
    const float* delta_pos = (const float*)d_in[3];
    const float* attn_mask = (const float*)d_in[4];
    const float* ln_g      = (const float*)d_in[5];
    const float* ln_b      = (const float*)d_in[6];
    const float* pn_g      = (const float*)d_in[7];
    const float* pn_b      = (const float*)d_in[8];
    const float* Wq        = (const float*)d_in[9];
    const float* Wk        = (const float*)d_in[10];
    const float* Wv        = (const float*)d_in[11];
    const float* Wbias     = (const float*)d_in[12];
    const float* bbias     = (const float*)d_in[13];
    const float* Wforce    = (const float*)d_in[14];
    float* out = (float*)d_out;
    float* ws  = (float*)d_ws;

    qkfv_kernel<<<512, 256, 0, stream>>>(query, ln_g, ln_b, Wq, Wk, Wv, Wforce,
                                         pn_g, pn_b, Wbias, bbias, ws);
    attn_force_kernel<<<NROW, 256, 0, stream>>>(pair, nlist, delta_pos, attn_mask,
                                                ws, out);
}